// Round 11
// baseline (49.243 us; speedup 1.0000x reference)
//
#include <hip/hip_runtime.h>
#include <hip/hip_bf16.h>
#include <stdint.h>

// Problem constants
#define NVOX   884736      // 96*96*96 voxels per batch
#define NB     32          // batches
#define NPTS   512         // MAX_POINTS
#define CAP    4096        // per-batch compact candidate capacity
#define THRV   0.9990234375f   // 1 - 2^-10 exactly; bits 0x3F7FC000; E[count]=864/batch
#define THR_TOP 0x3F7FFFFFu    // largest float bits < 1.0
#define BPB    216         // collect blocks per batch (4096 voxels each)
#define LBUF   80          // per-block LDS staging capacity (lambda=4)
#define NBUCK  128         // rank buckets
#define CNT_STRIDE 32      // pad per-batch counter to its own 128B line

#define C0c  0.28209479177387814f
#define C1c  0.4886025119029199f
#define C2c  0.6307831305050401f
#define SQ3c 1.7320508075688772f

typedef unsigned long long u64;
typedef unsigned int u32;

// ---------------------------------------------------------------------------
// Node 0: zero the per-batch counters (in-graph every call -> poison-safe)
// and build the collapsed scalar-path matrix M = (W1/4)(W2/sqrt32)(W3/8)
// with W2/W3 staged in LDS via float4 (the R10 one-block scalar-load build
// rode on k_collect's tail; this is ~1.5us standalone).
// ---------------------------------------------------------------------------
__global__ __launch_bounds__(256) void k_init(u32* __restrict__ cnt,
                                              const float* __restrict__ W1,
                                              const float* __restrict__ W2,
                                              const float* __restrict__ W3,
                                              float* __restrict__ Mg) {
  const int tid = threadIdx.x;
  __shared__ float w2[32 * 64];    // 8 KB
  __shared__ float w3[64 * 128];   // 32 KB
  __shared__ float Tm[16 * 64];    // 4 KB

  for (int i = tid; i < NB * CNT_STRIDE; i += 256) cnt[i] = 0u;

  // stage W2, W3 as float4
  for (int i = tid; i < 32 * 64 / 4; i += 256)
    reinterpret_cast<float4*>(w2)[i] = reinterpret_cast<const float4*>(W2)[i];
  for (int i = tid; i < 64 * 128 / 4; i += 256)
    reinterpret_cast<float4*>(w3)[i] = reinterpret_cast<const float4*>(W3)[i];
  __syncthreads();

  const float s1c = 1.0f / (4.0f * sqrtf(32.0f));
  for (int e = tid; e < 16 * 64; e += 256) {
    const int u = e >> 6, j = e & 63;
    float s = 0.f;
    for (int k = 0; k < 32; ++k) s += W1[u * 32 + k] * w2[k * 64 + j];
    Tm[e] = s * s1c;
  }
  __syncthreads();
  for (int e = tid; e < 16 * 128; e += 256) {
    const int u = e >> 7, vv = e & 127;
    float s = 0.f;
    for (int j = 0; j < 64; ++j) s += Tm[u * 64 + j] * w3[j * 128 + vv];
    Mg[e] = s * 0.125f;
  }
}

// ---------------------------------------------------------------------------
// Node 1: full scan of x. Per-block LDS aggregation, ONE global atomicAdd to
// reserve a contiguous segment of the per-batch compact array (216 atomics
// per 128B-padded line; ~3us tail, buys selfeat a coalesced gather and kills
// its 9-barrier count-scan). Overflow poisons the counter -> exact fallback.
// ---------------------------------------------------------------------------
__global__ __launch_bounds__(256) void k_collect(const float* __restrict__ x,
                                                 u64* __restrict__ cand,
                                                 u32* __restrict__ cnt) {
  const int b   = blockIdx.y;
  const int blk = blockIdx.x;
  const int tid = threadIdx.x;
  __shared__ u64 lbuf[LBUF];
  __shared__ int lcnt;
  __shared__ u32 gbase;
  if (tid == 0) lcnt = 0;
  __syncthreads();

  const float4* xb = reinterpret_cast<const float4*>(x + (size_t)b * NVOX);
  const int t0 = blk * 1024 + tid;                   // float4 index
  float4 q[4];
  #pragma unroll
  for (int it = 0; it < 4; ++it) q[it] = xb[t0 + it * 256];

  #pragma unroll
  for (int it = 0; it < 4; ++it) {
    const float4 qq = q[it];
    const u32 base = (u32)(t0 + it * 256) * 4u;
    if (qq.x >= THRV) { int p = atomicAdd(&lcnt, 1); if (p < LBUF) lbuf[p] = ((u64)__float_as_uint(qq.x) << 32) | (u64)(~(base      )); }
    if (qq.y >= THRV) { int p = atomicAdd(&lcnt, 1); if (p < LBUF) lbuf[p] = ((u64)__float_as_uint(qq.y) << 32) | (u64)(~(base + 1u)); }
    if (qq.z >= THRV) { int p = atomicAdd(&lcnt, 1); if (p < LBUF) lbuf[p] = ((u64)__float_as_uint(qq.z) << 32) | (u64)(~(base + 2u)); }
    if (qq.w >= THRV) { int p = atomicAdd(&lcnt, 1); if (p < LBUF) lbuf[p] = ((u64)__float_as_uint(qq.w) << 32) | (u64)(~(base + 3u)); }
  }
  __syncthreads();

  if (tid == 0) {
    int n = lcnt;
    if (n > LBUF) {                                  // impossible statistically; poison -> fallback
      gbase = atomicAdd(&cnt[b * CNT_STRIDE], (u32)LBUF);
      atomicAdd(&cnt[b * CNT_STRIDE], (u32)(CAP + 1));
    } else {
      gbase = n ? atomicAdd(&cnt[b * CNT_STRIDE], (u32)n) : 0u;
    }
  }
  __syncthreads();

  const int n = lcnt < LBUF ? lcnt : LBUF;
  if (tid < n) {
    const u32 p = gbase + (u32)tid;
    if (p < CAP) cand[(size_t)b * CAP + p] = lbuf[tid];
  }
}

// ---------------------------------------------------------------------------
// Node 2: 8 blocks per batch. Each block redundantly: coalesced gather of the
// compact candidate array (fused with LDS bucket counting) -> wave-0 shfl
// scan of 128 bucket counts (no barriers) -> scatter into bucket order ->
// exact within-bucket rank => sk = exact top-512 in jax.lax.top_k order
// (deterministic regardless of cand order) -> COM -> features for its own
// 64-point segment (-> output) -> partial max-pool. Exact histogram fallback.
// ---------------------------------------------------------------------------
__global__ __launch_bounds__(512) void k_selfeat(const float* __restrict__ x,
                                                 const u64* __restrict__ cand,
                                                 const u32* __restrict__ cnt,
                                                 const float* __restrict__ Mg,
                                                 float* __restrict__ ppart,
                                                 float* __restrict__ dout) {
  const int p8  = blockIdx.x;
  const int b   = blockIdx.y;
  const int tid = threadIdx.x;

  __shared__ u64 lk[CAP];          // 32 KB (also the fallback histogram)
  __shared__ u64 lk2[CAP];         // 32 KB bucket-ordered keys
  __shared__ u64 sk[NPTS];
  __shared__ u32 bc[NBUCK], bbx[NBUCK], bp[NBUCK];
  __shared__ float rbuf[8][4];
  __shared__ float comv[4];
  __shared__ float Ms[16 * 128];
  __shared__ __align__(16) float fsb[64][20];
  __shared__ float pr[4][128];
  __shared__ int sC;
  __shared__ u32 sthr;

  for (int e = tid; e < 16 * 128; e += 512) Ms[e] = Mg[e];
  if (tid < NBUCK) bc[tid] = 0u;
  __syncthreads();

  int C = (int)cnt[b * CNT_STRIDE];

  if (C >= NPTS && C <= CAP) {
    // ---- coalesced gather fused with bucket count ----
    for (int i = tid; i < C; i += 512) {
      const u64 k = cand[(size_t)b * CAP + i];
      lk[i] = k;
      u32 bk = (THR_TOP - (u32)(k >> 32)) >> 7; if (bk > (NBUCK - 1)) bk = NBUCK - 1;
      atomicAdd(&bc[bk], 1u);
    }
    __syncthreads();
  } else {
    // ---- exact fallback: fine histogram near 1.0 + re-collect ----
    u32* hist = reinterpret_cast<u32*>(lk);
    for (int i = tid; i < 4096; i += 512) hist[i] = 0u;
    __syncthreads();
    const u32* xb = reinterpret_cast<const u32*>(x) + (size_t)b * NVOX;
    for (int i = tid; i < NVOX; i += 512) {
      const u32 bits = xb[i];
      u32 key;
      if (bits >= 0x3F800000u) key = 0u;
      else { const u32 dd = THR_TOP - bits; key = dd >> 8; if (key > 4095u) key = 4095u; }
      atomicAdd(&hist[key], 1u);
    }
    __syncthreads();
    if (tid == 0) {
      u32 cum = 0; int kt = 4095;
      for (int k = 0; k < 4096; ++k) { cum += hist[k]; if (cum >= (u32)NPTS) { kt = k; break; } }
      sthr = (kt >= 4095) ? 0u : (0x3F800000u - ((u32)(kt + 1) << 8));
      sC = 0;
    }
    __syncthreads();
    const u32 thr = sthr;
    for (int i = tid; i < NVOX; i += 512) {
      const u32 bits = xb[i];
      if (bits >= thr) {
        const int p = atomicAdd(&sC, 1);
        if (p < CAP) lk[p] = ((u64)bits << 32) | (u64)(~(u32)i);
      }
    }
    __syncthreads();
    C = sC < CAP ? sC : CAP;
    // bucket count for fallback keys
    for (int i = tid; i < C; i += 512) {
      u32 bk = (THR_TOP - (u32)(lk[i] >> 32)) >> 7; if (bk > (NBUCK - 1)) bk = NBUCK - 1;
      atomicAdd(&bc[bk], 1u);
    }
    __syncthreads();
  }

  // ---- wave-0 shfl scan of 128 bucket counts (no internal barriers) ----
  if (tid < 64) {
    const u32 b0 = bc[2 * tid], b1 = bc[2 * tid + 1];
    const u32 s = b0 + b1;
    u32 incl = s;
    #pragma unroll
    for (int off = 1; off < 64; off <<= 1) {
      const u32 t = __shfl_up(incl, off, 64);
      if (tid >= off) incl += t;
    }
    const u32 excl = incl - s;
    bbx[2 * tid] = excl;       bbx[2 * tid + 1] = excl + b0;
    bp[2 * tid]  = excl;       bp[2 * tid + 1]  = excl + b0;
  }
  __syncthreads();

  // ---- scatter into bucket order ----
  for (int i = tid; i < C; i += 512) {
    const u64 ki = lk[i];
    u32 bk = (THR_TOP - (u32)(ki >> 32)) >> 7; if (bk > (NBUCK - 1)) bk = NBUCK - 1;
    const u32 p = atomicAdd(&bp[bk], 1u);
    lk2[p] = ki;
  }
  __syncthreads();

  // ---- exact rank within bucket (keys unique) ----
  for (int i = tid; i < C; i += 512) {
    const u64 ki = lk2[i];
    u32 bk = (THR_TOP - (u32)(ki >> 32)) >> 7; if (bk > (NBUCK - 1)) bk = NBUCK - 1;
    const u32 lo = bbx[bk], hi = lo + bc[bk];
    int rank = (int)lo;
    for (u32 j = lo; j < hi; ++j) rank += (lk2[j] > ki) ? 1 : 0;
    if (rank < NPTS) sk[rank] = ki;
  }
  __syncthreads();

  // ---- center of mass over the selected 512 ----
  {
    const u64 key = sk[tid];
    const u32 bits = (u32)(key >> 32);
    const u32 idx  = ~((u32)key);
    const float v  = __uint_as_float(bits);
    const u32 z = idx / 9216u, rem = idx % 9216u, yy = rem / 96u, xw = rem % 96u;
    const float p0 = ((float)z  - 48.f) / 48.f;
    const float p1 = ((float)yy - 48.f) / 48.f;
    const float p2 = ((float)xw - 48.f) / 48.f;
    float sv = v, s0 = p0 * v, s1 = p1 * v, s2 = p2 * v;
    for (int off = 32; off > 0; off >>= 1) {
      sv += __shfl_down(sv, off);
      s0 += __shfl_down(s0, off);
      s1 += __shfl_down(s1, off);
      s2 += __shfl_down(s2, off);
    }
    const int w = tid >> 6, ln = tid & 63;
    if (ln == 0) { rbuf[w][0] = sv; rbuf[w][1] = s0; rbuf[w][2] = s1; rbuf[w][3] = s2; }
    __syncthreads();
    if (tid == 0) {
      float tv = 0.f, t0s = 0.f, t1s = 0.f, t2s = 0.f;
      for (int wv = 0; wv < 8; ++wv) { tv += rbuf[wv][0]; t0s += rbuf[wv][1]; t1s += rbuf[wv][2]; t2s += rbuf[wv][3]; }
      const float dnm = fmaxf(tv, 1e-12f);
      comv[0] = t0s / dnm; comv[1] = t1s / dnm; comv[2] = t2s / dnm;
    }
    __syncthreads();
  }

  // ---- features for THIS block's 64-point segment (8 threads/point) ----
  const int pl = tid >> 3, cg = tid & 7;
  const int gp = b * NPTS + p8 * 64 + pl;
  const u64 key = sk[p8 * 64 + pl];
  const u32 bits = (u32)(key >> 32);
  const u32 idx  = ~((u32)key);
  const float v  = __uint_as_float(bits);
  const u32 z = idx / 9216u, rem = idx % 9216u, yy = rem / 96u, xw = rem % 96u;
  const float c0 = ((float)z  - 48.f) / 48.f - comv[0];
  const float c1 = ((float)yy - 48.f) / 48.f - comv[1];
  const float c2 = ((float)xw - 48.f) / 48.f - comv[2];
  const float r = fmaxf(sqrtf(c0 * c0 + c1 * c1 + c2 * c2), 1e-6f);
  const float inv = 1.0f / r;
  const float d0 = c0 * inv, d1 = c1 * inv, d2 = c2 * inv;
  const float v2 = v * v;
  const float rr2 = r * r;
  const float l1 = log1pf(r);
  const float er = expf(-r);
  const float sgv = 1.0f / (1.0f + expf(-v));
  const float sgr = 1.0f / (1.0f + expf(-r));

  float f[60];
  f[0]=v;      f[1]=r;      f[2]=C0c;     f[3]=v*r;
  f[4]=v2;     f[5]=l1;     f[6]=sqrtf(v + 1e-6f); f[7]=rr2;
  f[8]=v*C0c;  f[9]=er;     f[10]=v2*v;   f[11]=sqrtf(r);
  f[12]=v*l1;  f[13]=sgv;   f[14]=sgr;    f[15]=v*rr2;
  f[16]=c0;        f[17]=c1;        f[18]=c2;
  f[19]=c0*v;      f[20]=c1*v;      f[21]=c2*v;
  f[22]=C1c*d0;    f[23]=C1c*d1;    f[24]=C1c*d2;
  f[25]=c0*r;      f[26]=c1*r;      f[27]=c2*r;
  f[28]=d0;        f[29]=d1;        f[30]=d2;
  f[31]=d0*v;      f[32]=d1*v;      f[33]=d2*v;
  f[34]=c0*v2;     f[35]=c1*v2;     f[36]=c2*v2;
  f[37]=C1c*d0*r;  f[38]=C1c*d1*r;  f[39]=C1c*d2*r;
  const float t0 = C2c * (SQ3c * d0 * d2);
  const float t1 = C2c * (SQ3c * d0 * d1);
  const float t2_ = C2c * (d1 * d1 - 0.5f * (d0 * d0 + d2 * d2));
  const float t3 = C2c * (SQ3c * d1 * d2);
  const float t4 = C2c * (0.5f * SQ3c * (d2 * d2 - d0 * d0));
  f[40]=t0;     f[41]=t1;     f[42]=t2_;     f[43]=t3;     f[44]=t4;
  f[45]=t0*v;   f[46]=t1*v;   f[47]=t2_*v;   f[48]=t3*v;   f[49]=t4*v;
  f[50]=t0*r;   f[51]=t1*r;   f[52]=t2_*r;   f[53]=t3*r;   f[54]=t4*r;
  f[55]=t0*l1;  f[56]=t1*l1;  f[57]=t2_*l1;  f[58]=t3*l1;  f[59]=t4*l1;

  // feat output: chunk k written by thread with cg == k&7
  float4* ob = reinterpret_cast<float4*>(dout + 16384 + (size_t)gp * 60);
  #pragma unroll
  for (int k = 0; k < 15; ++k)
    if ((k & 7) == cg) ob[k] = make_float4(f[4*k], f[4*k+1], f[4*k+2], f[4*k+3]);

  #pragma unroll
  for (int k = 0; k < 4; ++k)
    if (k == cg) *reinterpret_cast<float4*>(&fsb[pl][k * 4]) =
        make_float4(f[4*k], f[4*k+1], f[4*k+2], f[4*k+3]);
  __syncthreads();

  // ---- partial pool: h3 = fs @ Ms, max over this block's 64 points ----
  const int g = tid >> 7, vv = tid & 127;
  float mreg[16];
  #pragma unroll
  for (int u = 0; u < 16; ++u) mreg[u] = Ms[u * 128 + vv];
  float pm = -3.4e38f;
  for (int n = g; n < 64; n += 4) {
    const float4 a0 = *reinterpret_cast<const float4*>(&fsb[n][0]);
    const float4 a1 = *reinterpret_cast<const float4*>(&fsb[n][4]);
    const float4 a2 = *reinterpret_cast<const float4*>(&fsb[n][8]);
    const float4 a3 = *reinterpret_cast<const float4*>(&fsb[n][12]);
    float acc = a0.x*mreg[0] + a0.y*mreg[1] + a0.z*mreg[2] + a0.w*mreg[3]
              + a1.x*mreg[4] + a1.y*mreg[5] + a1.z*mreg[6] + a1.w*mreg[7]
              + a2.x*mreg[8] + a2.y*mreg[9] + a2.z*mreg[10]+ a2.w*mreg[11]
              + a3.x*mreg[12]+ a3.y*mreg[13]+ a3.z*mreg[14]+ a3.w*mreg[15];
    pm = fmaxf(pm, acc);
  }
  pr[g][vv] = pm;
  __syncthreads();
  if (g == 0)
    ppart[((size_t)b * 8 + p8) * 128 + vv] =
        fmaxf(fmaxf(pr[0][vv], pr[1][vv]), fmaxf(pr[2][vv], pr[3][vv]));
}

// ---------------------------------------------------------------------------
// Node 3: reduce the 8 pooled partials per batch + head MLP -> logits.
// ---------------------------------------------------------------------------
__global__ __launch_bounds__(512) void k_head(const float* __restrict__ ppart,
                                              const float* __restrict__ fc1w,
                                              const float* __restrict__ fc1b,
                                              const float* __restrict__ fc2w,
                                              const float* __restrict__ fc2b,
                                              float* __restrict__ dout) {
  const int b = blockIdx.x;
  const int t = threadIdx.x;
  __shared__ float pl[128];
  __shared__ float hid[64];
  if (t < 128) {
    float m = -3.4e38f;
    #pragma unroll
    for (int k = 0; k < 8; ++k) m = fmaxf(m, ppart[((size_t)b * 8 + k) * 128 + t]);
    pl[t] = m;
  }
  __syncthreads();
  if (t < 64) {
    float sh = fc1b[t];
    for (int u = 0; u < 128; ++u) sh += pl[u] * fc1w[u * 64 + t];
    hid[t] = fmaxf(sh, 0.f);
  }
  __syncthreads();
  float sl = fc2b[t];
  for (int j = 0; j < 64; ++j) sl += hid[j] * fc2w[j * 512 + t];
  dout[b * 512 + t] = sl;
}

extern "C" void kernel_launch(void* const* d_in, const int* in_sizes, int n_in,
                              void* d_out, int out_size, void* d_ws, size_t ws_size,
                              hipStream_t stream) {
  const float* x    = (const float*)d_in[0];
  const float* W1   = (const float*)d_in[1];   // W1_0e (16,32)
  const float* W2   = (const float*)d_in[4];   // W2_0e (32,64)
  const float* W3   = (const float*)d_in[7];   // W3_0e (64,128)
  const float* fc1w = (const float*)d_in[8];
  const float* fc1b = (const float*)d_in[9];
  const float* fc2w = (const float*)d_in[10];
  const float* fc2b = (const float*)d_in[11];
  float* out = (float*)d_out;

  // workspace (~1.2 MB); counters zeroed in-graph by k_init every call.
  uint8_t* ws = (uint8_t*)d_ws;
  u32*   cnt   = (u32*)ws;                      // 32 x 128B-padded
  float* Mg    = (float*)(ws + 0x1000);         // 8 KB
  float* ppart = (float*)(ws + 0x4000);         // 32*8*128 f32 = 128 KB
  u64*   cand  = (u64*)(ws + 0x100000);         // 32*4096*8 = 1 MB

  k_init<<<1, 256, 0, stream>>>(cnt, W1, W2, W3, Mg);
  dim3 g1(BPB, NB);
  k_collect<<<g1, 256, 0, stream>>>(x, cand, cnt);
  dim3 g2(8, NB);
  k_selfeat<<<g2, 512, 0, stream>>>(x, cand, cnt, Mg, ppart, out);
  k_head<<<NB, 512, 0, stream>>>(ppart, fc1w, fc1b, fc2w, fc2b, out);
}

// Round 13
// 40.709 us; speedup vs baseline: 1.2096x; 1.2096x over previous
//
#include <hip/hip_runtime.h>
#include <hip/hip_bf16.h>
#include <stdint.h>

// Problem constants
#define NVOX   884736      // 96*96*96 voxels per batch
#define NB     32          // batches
#define NPTS   512         // MAX_POINTS
#define CAP    4096        // candidate capacity per batch
#define THRV   0.9990234375f   // 1 - 2^-10 exactly; bits 0x3F7FC000; E[count]=864/batch
#define THR_TOP 0x3F7FFFFFu    // largest float bits < 1.0
#define BPB    216         // collect blocks per batch (4096 voxels each)
#define SLOT   64          // per-block candidate slots (lambda=4, overflow astronomically unlikely)
#define LBUF   80          // LDS staging capacity
#define NBUCK  128         // rank buckets

#define C0c  0.28209479177387814f
#define C1c  0.4886025119029199f
#define C2c  0.6307831305050401f
#define SQ3c 1.7320508075688772f

typedef unsigned long long u64;
typedef unsigned int u32;

// ---------------------------------------------------------------------------
// Node 1: full scan of x -> per-block FIXED candidate slots (plain stores, no
// atomics). Block (0,0) also builds M = (W1/4)(W2/sqrt32)(W3/8) into ws.
// ---------------------------------------------------------------------------
__global__ __launch_bounds__(256) void k_collect(const float* __restrict__ x,
                                                 u64* __restrict__ cand,
                                                 u32* __restrict__ counts,
                                                 const float* __restrict__ W1,
                                                 const float* __restrict__ W2,
                                                 const float* __restrict__ W3,
                                                 float* __restrict__ Mg) {
  const int b   = blockIdx.y;
  const int blk = blockIdx.x;
  const int tid = threadIdx.x;
  __shared__ u64 lbuf[LBUF];
  __shared__ float Tm[16 * 64];
  __shared__ int lcnt;
  if (tid == 0) lcnt = 0;
  __syncthreads();

  const float4* xb = reinterpret_cast<const float4*>(x + (size_t)b * NVOX);
  const int t0 = blk * 1024 + tid;                   // float4 index
  float4 q[4];
  #pragma unroll
  for (int it = 0; it < 4; ++it) q[it] = xb[t0 + it * 256];

  #pragma unroll
  for (int it = 0; it < 4; ++it) {
    const float4 qq = q[it];
    const u32 base = (u32)(t0 + it * 256) * 4u;
    if (qq.x >= THRV) { int p = atomicAdd(&lcnt, 1); if (p < LBUF) lbuf[p] = ((u64)__float_as_uint(qq.x) << 32) | (u64)(~(base      )); }
    if (qq.y >= THRV) { int p = atomicAdd(&lcnt, 1); if (p < LBUF) lbuf[p] = ((u64)__float_as_uint(qq.y) << 32) | (u64)(~(base + 1u)); }
    if (qq.z >= THRV) { int p = atomicAdd(&lcnt, 1); if (p < LBUF) lbuf[p] = ((u64)__float_as_uint(qq.z) << 32) | (u64)(~(base + 2u)); }
    if (qq.w >= THRV) { int p = atomicAdd(&lcnt, 1); if (p < LBUF) lbuf[p] = ((u64)__float_as_uint(qq.w) << 32) | (u64)(~(base + 3u)); }
  }
  __syncthreads();

  const int slot = b * BPB + blk;
  const int n = lcnt;
  const int wn = (n <= SLOT) ? n : SLOT;
  if (tid < wn) cand[(size_t)slot * SLOT + tid] = lbuf[tid];
  if (tid == 0) counts[slot] = (n <= SLOT) ? (u32)n : (u32)(SLOT + 1);  // >SLOT => exact fallback

  if (blk == 0 && b == 0) {
    const float s1c = 1.0f / (4.0f * sqrtf(32.0f));
    for (int e = tid; e < 16 * 64; e += 256) {
      const int u = e >> 6, j = e & 63;
      float s = 0.f;
      for (int k = 0; k < 32; ++k) s += W1[u * 32 + k] * W2[k * 64 + j];
      Tm[e] = s * s1c;
    }
    __syncthreads();
    for (int e = tid; e < 16 * 128; e += 256) {
      const int u = e >> 7, vv = e & 127;
      float s = 0.f;
      for (int j = 0; j < 64; ++j) s += Tm[u * 64 + j] * W3[j * 128 + vv];
      Mg[e] = s * 0.125f;
    }
  }
}

// ---------------------------------------------------------------------------
// Node 2: 8 blocks per batch. Wave-shfl scan of slot counts (2 barriers) ->
// gather fused with bucket counting -> single-wave shfl scan of bucket
// counts -> scatter -> exact within-bucket rank => sk = exact top-512 in
// jax.lax.top_k order -> COM -> features for own 64-point segment
// (-> output) -> partial max-pool. Exact histogram fallback.
// R12 bug fixed: scnt/spref padded to 256 (spref[tid] was written for
// tid<256 but sized BPB=216 -> OOB into bc[] -> inf).
// ---------------------------------------------------------------------------
__global__ __launch_bounds__(512) void k_selfeat(const float* __restrict__ x,
                                                 const u64* __restrict__ cand,
                                                 const u32* __restrict__ counts,
                                                 const float* __restrict__ Mg,
                                                 float* __restrict__ ppart,
                                                 float* __restrict__ dout) {
  const int p8  = blockIdx.x;
  const int b   = blockIdx.y;
  const int tid = threadIdx.x;

  __shared__ u64 lk[CAP];          // 32 KB (also the fallback histogram)
  __shared__ u64 lk2[CAP];         // 32 KB bucket-ordered keys
  __shared__ u64 sk[NPTS];
  __shared__ u32 scnt[256], spref[256];   // padded to 256 (R12 OOB fix)
  __shared__ u32 bc[NBUCK], bbx[NBUCK], bp[NBUCK];
  __shared__ u32 wsum[4];
  __shared__ float rbuf[8][4];
  __shared__ float comv[4];
  __shared__ float Ms[16 * 128];
  __shared__ __align__(16) float fsb[64][20];
  __shared__ float pr[4][128];
  __shared__ int sbad, sC, stotal;
  __shared__ u32 sthr;

  for (int e = tid; e < 16 * 128; e += 512) Ms[e] = Mg[e];
  if (tid < NBUCK) bc[tid] = 0u;
  if (tid == 0) sbad = 0;

  // ---- wave-shfl scan of the 216 slot counts (threads 0..255, waves 0..3) --
  u32 myc = 0;
  if (tid < 256) myc = (tid < BPB) ? counts[b * BPB + tid] : 0u;
  __syncthreads();                                   // bc/sbad init + counts loaded
  if (tid < BPB && myc > SLOT) atomicOr(&sbad, 1);
  if (tid < 256) {
    u32 incl = myc;
    #pragma unroll
    for (int off = 1; off < 64; off <<= 1) {
      const u32 t = __shfl_up(incl, off, 64);
      if ((tid & 63) >= off) incl += t;
    }
    if ((tid & 63) == 63) wsum[tid >> 6] = incl;
    scnt[tid] = myc;
    spref[tid] = incl - myc;                         // intra-wave exclusive (temp)
  }
  __syncthreads();
  if (tid < 256) {
    u32 offp = 0;
    const int w = tid >> 6;
    #pragma unroll
    for (int i = 0; i < 4; ++i) if (i < w) offp += wsum[i];
    spref[tid] += offp;
  }
  if (tid == 0) stotal = (int)(wsum[0] + wsum[1] + wsum[2] + wsum[3]);
  __syncthreads();
  const int total = stotal;

  int C;
  if (!sbad && total >= NPTS && total <= CAP) {
    C = total;
    // ---- gather (2 threads/slot) fused with bucket counting ----
    for (int s = tid >> 1; s < BPB; s += 256) {
      const u32 c = scnt[s], p = spref[s];
      const u64* src = cand + (size_t)(b * BPB + s) * SLOT;
      for (u32 k = (u32)(tid & 1); k < c; k += 2) {
        const u64 kk = src[k];
        lk[p + k] = kk;
        u32 bk = (THR_TOP - (u32)(kk >> 32)) >> 7; if (bk > (NBUCK - 1)) bk = NBUCK - 1;
        atomicAdd(&bc[bk], 1u);
      }
    }
    __syncthreads();
  } else {
    // ---- exact fallback: fine histogram near 1.0 + re-collect ----
    u32* hist = reinterpret_cast<u32*>(lk);
    for (int i = tid; i < 4096; i += 512) hist[i] = 0u;
    __syncthreads();
    const u32* xb = reinterpret_cast<const u32*>(x) + (size_t)b * NVOX;
    for (int i = tid; i < NVOX; i += 512) {
      const u32 bits = xb[i];
      u32 key;
      if (bits >= 0x3F800000u) key = 0u;
      else { const u32 dd = THR_TOP - bits; key = dd >> 8; if (key > 4095u) key = 4095u; }
      atomicAdd(&hist[key], 1u);
    }
    __syncthreads();
    if (tid == 0) {
      u32 cum = 0; int kt = 4095;
      for (int k = 0; k < 4096; ++k) { cum += hist[k]; if (cum >= (u32)NPTS) { kt = k; break; } }
      sthr = (kt >= 4095) ? 0u : (0x3F800000u - ((u32)(kt + 1) << 8));
      sC = 0;
    }
    __syncthreads();
    const u32 thr = sthr;
    for (int i = tid; i < NVOX; i += 512) {
      const u32 bits = xb[i];
      if (bits >= thr) {
        const int p = atomicAdd(&sC, 1);
        if (p < CAP) lk[p] = ((u64)bits << 32) | (u64)(~(u32)i);
      }
    }
    __syncthreads();
    C = sC < CAP ? sC : CAP;
    for (int i = tid; i < C; i += 512) {             // bucket count for fallback keys
      u32 bk = (THR_TOP - (u32)(lk[i] >> 32)) >> 7; if (bk > (NBUCK - 1)) bk = NBUCK - 1;
      atomicAdd(&bc[bk], 1u);
    }
    __syncthreads();
  }

  // ---- single-wave shfl scan of 128 bucket counts (no internal barriers) --
  if (tid < 64) {
    const u32 b0 = bc[2 * tid], b1 = bc[2 * tid + 1];
    const u32 s = b0 + b1;
    u32 incl = s;
    #pragma unroll
    for (int off = 1; off < 64; off <<= 1) {
      const u32 t = __shfl_up(incl, off, 64);
      if (tid >= off) incl += t;
    }
    const u32 excl = incl - s;
    bbx[2 * tid] = excl;       bbx[2 * tid + 1] = excl + b0;
    bp[2 * tid]  = excl;       bp[2 * tid + 1]  = excl + b0;
  }
  __syncthreads();

  // ---- scatter into bucket order ----
  for (int i = tid; i < C; i += 512) {
    const u64 ki = lk[i];
    u32 bk = (THR_TOP - (u32)(ki >> 32)) >> 7; if (bk > (NBUCK - 1)) bk = NBUCK - 1;
    const u32 p = atomicAdd(&bp[bk], 1u);
    lk2[p] = ki;
  }
  __syncthreads();

  // ---- exact rank within bucket (keys unique) ----
  for (int i = tid; i < C; i += 512) {
    const u64 ki = lk2[i];
    u32 bk = (THR_TOP - (u32)(ki >> 32)) >> 7; if (bk > (NBUCK - 1)) bk = NBUCK - 1;
    const u32 lo = bbx[bk], hi = lo + bc[bk];
    int rank = (int)lo;
    for (u32 j = lo; j < hi; ++j) rank += (lk2[j] > ki) ? 1 : 0;
    if (rank < NPTS) sk[rank] = ki;
  }
  __syncthreads();

  // ---- center of mass over the selected 512 ----
  {
    const u64 key = sk[tid];
    const u32 bits = (u32)(key >> 32);
    const u32 idx  = ~((u32)key);
    const float v  = __uint_as_float(bits);
    const u32 z = idx / 9216u, rem = idx % 9216u, yy = rem / 96u, xw = rem % 96u;
    const float p0 = ((float)z  - 48.f) / 48.f;
    const float p1 = ((float)yy - 48.f) / 48.f;
    const float p2 = ((float)xw - 48.f) / 48.f;
    float sv = v, s0 = p0 * v, s1 = p1 * v, s2 = p2 * v;
    for (int off = 32; off > 0; off >>= 1) {
      sv += __shfl_down(sv, off);
      s0 += __shfl_down(s0, off);
      s1 += __shfl_down(s1, off);
      s2 += __shfl_down(s2, off);
    }
    const int w = tid >> 6, ln = tid & 63;
    if (ln == 0) { rbuf[w][0] = sv; rbuf[w][1] = s0; rbuf[w][2] = s1; rbuf[w][3] = s2; }
    __syncthreads();
    if (tid == 0) {
      float tv = 0.f, t0s = 0.f, t1s = 0.f, t2s = 0.f;
      for (int wv = 0; wv < 8; ++wv) { tv += rbuf[wv][0]; t0s += rbuf[wv][1]; t1s += rbuf[wv][2]; t2s += rbuf[wv][3]; }
      const float dnm = fmaxf(tv, 1e-12f);
      comv[0] = t0s / dnm; comv[1] = t1s / dnm; comv[2] = t2s / dnm;
    }
    __syncthreads();
  }

  // ---- features for THIS block's 64-point segment (8 threads/point) ----
  const int pl = tid >> 3, cg = tid & 7;
  const int gp = b * NPTS + p8 * 64 + pl;
  const u64 key = sk[p8 * 64 + pl];
  const u32 bits = (u32)(key >> 32);
  const u32 idx  = ~((u32)key);
  const float v  = __uint_as_float(bits);
  const u32 z = idx / 9216u, rem = idx % 9216u, yy = rem / 96u, xw = rem % 96u;
  const float c0 = ((float)z  - 48.f) / 48.f - comv[0];
  const float c1 = ((float)yy - 48.f) / 48.f - comv[1];
  const float c2 = ((float)xw - 48.f) / 48.f - comv[2];
  const float r = fmaxf(sqrtf(c0 * c0 + c1 * c1 + c2 * c2), 1e-6f);
  const float inv = 1.0f / r;
  const float d0 = c0 * inv, d1 = c1 * inv, d2 = c2 * inv;
  const float v2 = v * v;
  const float rr2 = r * r;
  const float l1 = log1pf(r);
  const float er = expf(-r);
  const float sgv = 1.0f / (1.0f + expf(-v));
  const float sgr = 1.0f / (1.0f + expf(-r));

  float f[60];
  f[0]=v;      f[1]=r;      f[2]=C0c;     f[3]=v*r;
  f[4]=v2;     f[5]=l1;     f[6]=sqrtf(v + 1e-6f); f[7]=rr2;
  f[8]=v*C0c;  f[9]=er;     f[10]=v2*v;   f[11]=sqrtf(r);
  f[12]=v*l1;  f[13]=sgv;   f[14]=sgr;    f[15]=v*rr2;
  f[16]=c0;        f[17]=c1;        f[18]=c2;
  f[19]=c0*v;      f[20]=c1*v;      f[21]=c2*v;
  f[22]=C1c*d0;    f[23]=C1c*d1;    f[24]=C1c*d2;
  f[25]=c0*r;      f[26]=c1*r;      f[27]=c2*r;
  f[28]=d0;        f[29]=d1;        f[30]=d2;
  f[31]=d0*v;      f[32]=d1*v;      f[33]=d2*v;
  f[34]=c0*v2;     f[35]=c1*v2;     f[36]=c2*v2;
  f[37]=C1c*d0*r;  f[38]=C1c*d1*r;  f[39]=C1c*d2*r;
  const float t0 = C2c * (SQ3c * d0 * d2);
  const float t1 = C2c * (SQ3c * d0 * d1);
  const float t2_ = C2c * (d1 * d1 - 0.5f * (d0 * d0 + d2 * d2));
  const float t3 = C2c * (SQ3c * d1 * d2);
  const float t4 = C2c * (0.5f * SQ3c * (d2 * d2 - d0 * d0));
  f[40]=t0;     f[41]=t1;     f[42]=t2_;     f[43]=t3;     f[44]=t4;
  f[45]=t0*v;   f[46]=t1*v;   f[47]=t2_*v;   f[48]=t3*v;   f[49]=t4*v;
  f[50]=t0*r;   f[51]=t1*r;   f[52]=t2_*r;   f[53]=t3*r;   f[54]=t4*r;
  f[55]=t0*l1;  f[56]=t1*l1;  f[57]=t2_*l1;  f[58]=t3*l1;  f[59]=t4*l1;

  // feat output: chunk k written by thread with cg == k&7
  float4* ob = reinterpret_cast<float4*>(dout + 16384 + (size_t)gp * 60);
  #pragma unroll
  for (int k = 0; k < 15; ++k)
    if ((k & 7) == cg) ob[k] = make_float4(f[4*k], f[4*k+1], f[4*k+2], f[4*k+3]);

  #pragma unroll
  for (int k = 0; k < 4; ++k)
    if (k == cg) *reinterpret_cast<float4*>(&fsb[pl][k * 4]) =
        make_float4(f[4*k], f[4*k+1], f[4*k+2], f[4*k+3]);
  __syncthreads();

  // ---- partial pool: h3 = fs @ Ms, max over this block's 64 points ----
  const int g = tid >> 7, vv = tid & 127;
  float mreg[16];
  #pragma unroll
  for (int u = 0; u < 16; ++u) mreg[u] = Ms[u * 128 + vv];
  float pm = -3.4e38f;
  for (int n = g; n < 64; n += 4) {
    const float4 a0 = *reinterpret_cast<const float4*>(&fsb[n][0]);
    const float4 a1 = *reinterpret_cast<const float4*>(&fsb[n][4]);
    const float4 a2 = *reinterpret_cast<const float4*>(&fsb[n][8]);
    const float4 a3 = *reinterpret_cast<const float4*>(&fsb[n][12]);
    float acc = a0.x*mreg[0] + a0.y*mreg[1] + a0.z*mreg[2] + a0.w*mreg[3]
              + a1.x*mreg[4] + a1.y*mreg[5] + a1.z*mreg[6] + a1.w*mreg[7]
              + a2.x*mreg[8] + a2.y*mreg[9] + a2.z*mreg[10]+ a2.w*mreg[11]
              + a3.x*mreg[12]+ a3.y*mreg[13]+ a3.z*mreg[14]+ a3.w*mreg[15];
    pm = fmaxf(pm, acc);
  }
  pr[g][vv] = pm;
  __syncthreads();
  if (g == 0)
    ppart[((size_t)b * 8 + p8) * 128 + vv] =
        fmaxf(fmaxf(pr[0][vv], pr[1][vv]), fmaxf(pr[2][vv], pr[3][vv]));
}

// ---------------------------------------------------------------------------
// Node 3: reduce the 8 pooled partials per batch + head MLP -> logits.
// ---------------------------------------------------------------------------
__global__ __launch_bounds__(512) void k_head(const float* __restrict__ ppart,
                                              const float* __restrict__ fc1w,
                                              const float* __restrict__ fc1b,
                                              const float* __restrict__ fc2w,
                                              const float* __restrict__ fc2b,
                                              float* __restrict__ dout) {
  const int b = blockIdx.x;
  const int t = threadIdx.x;
  __shared__ float pl[128];
  __shared__ float hid[64];
  if (t < 128) {
    float m = -3.4e38f;
    #pragma unroll
    for (int k = 0; k < 8; ++k) m = fmaxf(m, ppart[((size_t)b * 8 + k) * 128 + t]);
    pl[t] = m;
  }
  __syncthreads();
  if (t < 64) {
    float sh = fc1b[t];
    for (int u = 0; u < 128; ++u) sh += pl[u] * fc1w[u * 64 + t];
    hid[t] = fmaxf(sh, 0.f);
  }
  __syncthreads();
  float sl = fc2b[t];
  for (int j = 0; j < 64; ++j) sl += hid[j] * fc2w[j * 512 + t];
  dout[b * 512 + t] = sl;
}

extern "C" void kernel_launch(void* const* d_in, const int* in_sizes, int n_in,
                              void* d_out, int out_size, void* d_ws, size_t ws_size,
                              hipStream_t stream) {
  const float* x    = (const float*)d_in[0];
  const float* W1   = (const float*)d_in[1];   // W1_0e (16,32)
  const float* W2   = (const float*)d_in[4];   // W2_0e (32,64)
  const float* W3   = (const float*)d_in[7];   // W3_0e (64,128)
  const float* fc1w = (const float*)d_in[8];
  const float* fc1b = (const float*)d_in[9];
  const float* fc2w = (const float*)d_in[10];
  const float* fc2b = (const float*)d_in[11];
  float* out = (float*)d_out;

  // workspace (~3.8 MB); every read location is rewritten earlier in the same
  // call -> no cross-replay state, poison-safe.
  uint8_t* ws = (uint8_t*)d_ws;
  u32*   counts = (u32*)ws;                     // 6912 u32
  u64*   cand   = (u64*)(ws + 0x10000);         // 6912*64*8 = 3.54 MB
  float* ppart  = (float*)(ws + 0x3A0000);      // 32*8*128 f32 = 128 KB
  float* Mg     = (float*)(ws + 0x3C0000);      // 16*128 f32 = 8 KB

  dim3 g1(BPB, NB);
  k_collect<<<g1, 256, 0, stream>>>(x, cand, counts, W1, W2, W3, Mg);
  dim3 g2(8, NB);
  k_selfeat<<<g2, 512, 0, stream>>>(x, cand, counts, Mg, ppart, out);
  k_head<<<NB, 512, 0, stream>>>(ppart, fc1w, fc1b, fc2w, fc2b, out);
}